// Round 2
// baseline (198.151 us; speedup 1.0000x reference)
//
#include <hip/hip_runtime.h>

namespace {
constexpr int IW = 512;
constexpr int IH = 512;
constexpr int ID = 64;
constexpr int PS = IH * IW;                      // plane stride (floats)
constexpr float W_Z  = 0.5f;                     // CONTIZ^2
constexpr float W_XY = 2.0f;
constexpr float W_XZ = 1.41421356237309515f;     // 2*CONTIZ = sqrt(2)

constexpr int TPB    = 256;
constexpr int BLOCKS = 1024;    // 2(n) x 2(seg) x 512(h) x 128(chunk) / TPB
constexpr int DSEG   = ID / 2;  // 32 d-steps per segment
}

// packed-fp32 friendly 2-wide vector (v_pk_* on CDNA)
using v2f = __attribute__((ext_vector_type(2))) float;

__device__ __forceinline__ v2f pabs2(v2f t) {
    // |t| = max(t, -t): neg folds into v_pk_max_f32 src modifier
    return __builtin_elementwise_max(t, -t);
}

// min 4 waves/EU -> VGPR <= 128 -> 16 waves/CU despite pipeline state
__global__ __launch_bounds__(TPB, 4) void HessianReg_kernel(const float* __restrict__ img,
                                                            float* __restrict__ out) {
    // XCD swizzle: each XCD owns 128 consecutive logical blocks -> y-neighbor
    // rows stay in the same XCD's L2 (reuse window ~1.5 MB < 4 MiB L2).
    const int lblk = (blockIdx.x & 7) * (BLOCKS / 8) + (blockIdx.x >> 3);
    const int t     = lblk * TPB + threadIdx.x;
    const int chunk = t & 127;          // float4 index within row
    const int r     = t >> 7;
    const int h     = r & (IH - 1);     // wave-uniform (128 chunks = 2 waves/row)
    const int q     = r >> 9;           // [0,4)
    const int n     = q & 1;
    const int seg   = q >> 1;
    const int d0    = __builtin_amdgcn_readfirstlane(seg * DSEG);
    const int w0    = chunk << 2;

    const bool hasW = (chunk < 127);
    const bool hy2  = (h < IH - 1);     // wave-uniform
    const bool hy3  = (h < IH - 2);     // wave-uniform

    const float mh = hasW ? 1.f : 0.f;  // mask for x-tail terms (chunk 127)
    const v2f  mv  = {1.f, mh};
    // clamped tail offset: chunk 127 re-reads its own row start (in-bounds,
    // finite garbage) and every consumer is mh/mv-masked -> no divergent
    // branches around the tail loads.
    const int  tsh = hasW ? 4 : 0;

    const float* p0 = img + (size_t)(n * (ID * PS) + (d0 * IH + h) * IW + w0);

    const float4 Z4 = make_float4(0.f, 0.f, 0.f, 0.f);
    const float2 Z2 = make_float2(0.f, 0.f);

    // ---- prologue: rows A=(d0,h), B=(d0,h+1), E=(d0+1,h) -> rolling diffs ----
    float4 A   = *(const float4*)p0;
    float2 a45 = *(const float2*)(p0 + tsh);
    float4 B = Z4; float b4 = 0.f;
    if (hy2) { B = *(const float4*)(p0 + IW); b4 = p0[IW + tsh]; }
    float4 E   = *(const float4*)(p0 + PS);            // d0+1 <= 33: valid
    float2 e45 = *(const float2*)(p0 + PS + tsh);

    // x first-differences (tail entries garbage -> masked at use)
    v2f   dxA0 = {A.y - A.x, A.z - A.y};
    v2f   dxA1 = {A.w - A.z, a45.x - A.w};
    float dxA4 = a45.y - a45.x;
    v2f   dxB0 = {B.y - B.x, B.z - B.y};
    v2f   dxB1 = {B.w - B.z, b4 - B.w};
    v2f   dxE0 = {E.y - E.x, E.z - E.y};
    v2f   dxE1 = {E.w - E.z, e45.x - E.w};
    float dxE4 = e45.y - e45.x;

    v2f B0v = {B.x, B.y}, B1v = {B.z, B.w};
    v2f E0v = {E.x, E.y}, E1v = {E.z, E.w};
    v2f A0v = {A.x, A.y}, A1v = {A.z, A.w};
    v2f dy10 = B0v - A0v, dy11 = B1v - A1v;   // dy1 = B - A
    v2f dz10 = E0v - A0v, dz11 = E1v - A1v;   // dz1 = E - A

    // ---- pipeline prologue ----
    // Cc/Gc/Fc feed step 0; Fn feeds step 1 (F = leading plane = HBM first
    // touch ~900cy -> needs 2-iteration cover; C,G are L2 hits ~300cy -> 1).
    float4 Cc = Z4;
    if (hy3) Cc = *(const float4*)(p0 + 2 * IW);
    float4 Gc = Z4; float g4c = 0.f;
    if (hy2) { Gc = *(const float4*)(p0 + PS + IW); g4c = p0[PS + IW + tsh]; } // gz2(0) always true
    float4 Fc = *(const float4*)(p0 + 2 * PS);                                 // gz3(0): d0<62 always
    float2 f45c = *(const float2*)(p0 + 2 * PS + tsh);
    float4 Fn = *(const float4*)(p0 + 3 * PS);                                 // gz3(1): d0+1<62 always
    float2 f45n = *(const float2*)(p0 + 3 * PS + tsh);

    // weight-separated accumulators
    float a1s = 0.f;                           // g_xx
    v2f acc1 = {0.f, 0.f};                     // g_yy            (w=1)
    v2f accz = {0.f, 0.f};                     // g_zz            (w=0.5)
    v2f acc2 = {0.f, 0.f};                     // g_xy            (w=2)
    v2f accs = {0.f, 0.f};                     // g_xz + g_yz     (w=sqrt2)

    #pragma unroll 2
    for (int dl = 0; dl < DSEG; ++dl) {
        const int d = d0 + dl;
        const bool gz2 = (d < ID - 1);  // wave-uniform accumulate guards
        const bool gz3 = (d < ID - 2);

        // ---- issue prefetches FIRST (max distance to use) ----
        // C,G for step dl+1 ; F for step dl+2. Guards keep every issued
        // address inside plane <= 63.
        const bool pC = (dl + 1 < DSEG) && hy3;   // plane d+1, row h+2
        const bool pG = (d + 1 < ID - 1) && hy2;  // plane d+2, row h+1
        const bool pF = (d + 2 < ID - 2);         // plane d+4, row h
        float4 Cn = Z4;
        if (pC) Cn = *(const float4*)(p0 + PS + 2 * IW);
        float4 Gn = Z4; float g4n = 0.f;
        if (pG) { Gn = *(const float4*)(p0 + 2 * PS + IW); g4n = p0[2 * PS + IW + tsh]; }
        float4 Fn2 = Z4; float2 f45n2 = Z2;
        if (pF) { Fn2 = *(const float4*)(p0 + 4 * PS); f45n2 = *(const float2*)(p0 + 4 * PS + tsh); }

        // ---- stencils from rolled state only ----
        {   // g_xx: |dx[w+1]-dx[w]|, last two terms masked on boundary lane
            float t0 = dxA0.y - dxA0.x;
            float t1 = dxA1.x - dxA0.y;
            float t2 = dxA1.y - dxA1.x;
            float t3 = dxA4   - dxA1.y;
            a1s += fabsf(t0);
            a1s += fabsf(t1);
            a1s  = fmaf(mh, fabsf(t2), a1s);
            a1s  = fmaf(mh, fabsf(t3), a1s);
        }
        if (hy2) {                // g_xy = |dxB - dxA|
            acc2 += pabs2(dxB0 - dxA0);
            acc2 += mv * pabs2(dxB1 - dxA1);
        }
        if (gz2) {                // g_xz = |dxE - dxA|
            accs += pabs2(dxE0 - dxA0);
            accs += mv * pabs2(dxE1 - dxA1);
        }

        // ---- fresh first-differences from pipelined regs ----
        v2f   dxF0 = {Fc.y - Fc.x, Fc.z - Fc.y};
        v2f   dxF1 = {Fc.w - Fc.z, f45c.x - Fc.w};
        float dxF4 = f45c.y - f45c.x;
        v2f   dxG0 = {Gc.y - Gc.x, Gc.z - Gc.y};
        v2f   dxG1 = {Gc.w - Gc.z, g4c - Gc.w};
        v2f C0v = {Cc.x, Cc.y}, C1v = {Cc.z, Cc.w};
        v2f G0v = {Gc.x, Gc.y}, G1v = {Gc.z, Gc.w};
        v2f F0v = {Fc.x, Fc.y}, F1v = {Fc.z, Fc.w};
        v2f dy20  = C0v - B0v, dy21  = C1v - B1v;   // dy2  = C - B
        v2f dyEG0 = G0v - E0v, dyEG1 = G1v - E1v;   // dyEG = G - E
        v2f dz20  = F0v - E0v, dz21  = F1v - E1v;   // dz2  = F - E

        if (hy3) {                // g_yy = |dy2 - dy1|
            acc1 += pabs2(dy20 - dy10);
            acc1 += pabs2(dy21 - dy11);
        }
        if (gz3) {                // g_zz = |dz2 - dz1|
            accz += pabs2(dz20 - dz10);
            accz += pabs2(dz21 - dz11);
        }
        if (gz2 && hy2) {         // g_yz = |dyEG - dy1|
            accs += pabs2(dyEG0 - dy10);
            accs += pabs2(dyEG1 - dy11);
        }

        // ---- roll z + shift pipeline (renamed away by unroll) ----
        dxA0 = dxE0; dxA1 = dxE1; dxA4 = dxE4;
        dxE0 = dxF0; dxE1 = dxF1; dxE4 = dxF4;
        dxB0 = dxG0; dxB1 = dxG1;
        dy10 = dyEG0; dy11 = dyEG1;
        dz10 = dz20;  dz11 = dz21;
        B0v = G0v; B1v = G1v;
        E0v = F0v; E1v = F1v;
        Cc = Cn; Gc = Gn; g4c = g4n;
        Fc = Fn; f45c = f45n;
        Fn = Fn2; f45n = f45n2;
        p0 += PS;
    }

    float acc = a1s + acc1.x + acc1.y
              + W_Z  * (accz.x + accz.y)
              + W_XY * (acc2.x + acc2.y)
              + W_XZ * (accs.x + accs.y);

    // wave (64-lane) shuffle reduce
    for (int off = 32; off > 0; off >>= 1)
        acc += __shfl_down(acc, off, 64);

    __shared__ float ws[TPB / 64];
    const int lane = threadIdx.x & 63;
    const int wv   = threadIdx.x >> 6;
    if (lane == 0) ws[wv] = acc;
    __syncthreads();
    if (threadIdx.x == 0) {
        float bsum = 0.f;
        #pragma unroll
        for (int i = 0; i < TPB / 64; ++i) bsum += ws[i];
        atomicAdd(out, bsum * (1.0f / (IH * IW)));
    }
}

extern "C" void kernel_launch(void* const* d_in, const int* in_sizes, int n_in,
                              void* d_out, int out_size, void* d_ws, size_t ws_size,
                              hipStream_t stream) {
    const float* img = (const float*)d_in[0];
    float* out = (float*)d_out;
    // d_out is re-poisoned to 0xAA before every timed launch -> zero it on-stream.
    hipMemsetAsync(out, 0, sizeof(float), stream);
    hipLaunchKernelGGL(HessianReg_kernel, dim3(BLOCKS), dim3(TPB), 0, stream, img, out);
}